// Round 2
// baseline (6132.186 us; speedup 1.0000x reference)
//
#include <hip/hip_runtime.h>
#include <hip/hip_fp16.h>
#include <math.h>

#define T_LEN 2500
#define BATCH 64
#define CH    12
#define HID   64
#define G4    256   // 4*H
#define D2    128   // 2*H
#define NROW  (T_LEN*BATCH)

__device__ __forceinline__ float rcp_(float x){ return __builtin_amdgcn_rcpf(x); }
__device__ __forceinline__ float sig_(float x){ return rcp_(1.f + __expf(-x)); }
__device__ __forceinline__ float tanh_(float x){ return fmaf(-2.f, rcp_(1.f + __expf(2.f*x)), 1.f); }

__device__ __forceinline__ float ldv(const float* p){ return *p; }
__device__ __forceinline__ float ldv(const __half* p){ return __half2float(*p); }
__device__ __forceinline__ void stv(float* p, float v){ *p = v; }
__device__ __forceinline__ void stv(__half* p, float v){ *p = __float2half(v); }

// 4 independent FMA chains over K=64 from LDS-broadcast h.
__device__ __forceinline__ float hh_dot(const float* h_lds, const float* w, float seed) {
  float s0 = seed, s1 = 0.f, s2 = 0.f, s3 = 0.f;
#pragma unroll
  for (int k = 0; k < HID; k += 16) {
    float4 a0 = *reinterpret_cast<const float4*>(&h_lds[k]);
    float4 a1 = *reinterpret_cast<const float4*>(&h_lds[k + 4]);
    float4 a2 = *reinterpret_cast<const float4*>(&h_lds[k + 8]);
    float4 a3 = *reinterpret_cast<const float4*>(&h_lds[k + 12]);
    s0 = fmaf(a0.x, w[k], s0);      s0 = fmaf(a0.y, w[k + 1], s0);
    s0 = fmaf(a0.z, w[k + 2], s0);  s0 = fmaf(a0.w, w[k + 3], s0);
    s1 = fmaf(a1.x, w[k + 4], s1);  s1 = fmaf(a1.y, w[k + 5], s1);
    s1 = fmaf(a1.z, w[k + 6], s1);  s1 = fmaf(a1.w, w[k + 7], s1);
    s2 = fmaf(a2.x, w[k + 8], s2);  s2 = fmaf(a2.y, w[k + 9], s2);
    s2 = fmaf(a2.z, w[k + 10], s2); s2 = fmaf(a2.w, w[k + 11], s2);
    s3 = fmaf(a3.x, w[k + 12], s3); s3 = fmaf(a3.y, w[k + 13], s3);
    s3 = fmaf(a3.z, w[k + 14], s3); s3 = fmaf(a3.w, w[k + 15], s3);
  }
  return (s0 + s1) + (s2 + s3);
}

// ---------------------------------------------------------------------------
// Fold input projection into layer-0 input weights.
//   w0p[d][g][c] = sum_j w_ih0[d][g][j]*Wp[j][c]
//   b0p[d][g]    = b_ih0[d][g]+b_hh0[d][g]+sum_j w_ih0[d][g][j]*bp[j]
// ---------------------------------------------------------------------------
__global__ void k_prep0(const float* __restrict__ Wp, const float* __restrict__ bp,
                        const float* __restrict__ w_ih0,
                        const float* __restrict__ b_ih0, const float* __restrict__ b_hh0,
                        float* __restrict__ w0p, float* __restrict__ b0p) {
  int tid = blockIdx.x * blockDim.x + threadIdx.x;
  if (tid >= 2 * G4) return;
  const float* wih = w_ih0 + (size_t)tid * HID;
  float bb = b_ih0[tid] + b_hh0[tid];
  for (int j = 0; j < HID; ++j) bb += wih[j] * bp[j];
  b0p[tid] = bb;
  for (int c = 0; c < CH; ++c) {
    float s = 0.f;
    for (int j = 0; j < HID; ++j) s += wih[j] * Wp[j * CH + c];
    w0p[(size_t)tid * CH + c] = s;
  }
}

// ---------------------------------------------------------------------------
// Layer-0 recurrence: xw computed inline from x (12 FMAs). One WG per (dir,b).
// ---------------------------------------------------------------------------
template<typename ST>
__global__ __launch_bounds__(256) void k_recur0(const float* __restrict__ x,
                                                const float* __restrict__ w0p,
                                                const float* __restrict__ b0p,
                                                const float* __restrict__ whh,
                                                ST* __restrict__ seq) {
  int wg = blockIdx.x, dir = wg >> 6, b = wg & 63, g = threadIdx.x;
  const float* W = whh + (size_t)(dir * G4 + g) * HID;
  float w[HID];
#pragma unroll
  for (int k = 0; k < HID; ++k) w[k] = W[k];
  float w0[CH];
  const float* wp = w0p + (size_t)(dir * G4 + g) * CH;
#pragma unroll
  for (int c = 0; c < CH; ++c) w0[c] = wp[c];
  float bb = b0p[dir * G4 + g];

  __shared__ __align__(16) float h_lds[HID];
  __shared__ float gates[G4];
  __shared__ __align__(16) float xs[2][16];

  int t0 = dir ? (T_LEN - 1) : 0;
  int dt = dir ? -1 : 1;
  if (g < HID) h_lds[g] = 0.f;
  float xreg = 0.f;
  if (g < CH) {
    xs[0][g] = x[((size_t)b * CH + g) * T_LEN + t0];
    xreg     = x[((size_t)b * CH + g) * T_LEN + t0 + dt];
  }
  float c = 0.f;
  __syncthreads();

  int t = t0;
  for (int it = 0; it < T_LEN; ++it) {
    int cur = it & 1, nxt = cur ^ 1;
    float4 xa = *reinterpret_cast<const float4*>(&xs[cur][0]);
    float4 xb = *reinterpret_cast<const float4*>(&xs[cur][4]);
    float4 xc = *reinterpret_cast<const float4*>(&xs[cur][8]);
    float p0 = bb, p1 = 0.f, p2 = 0.f;
    p0 = fmaf(xa.x, w0[0], p0); p0 = fmaf(xa.y, w0[1], p0);
    p0 = fmaf(xa.z, w0[2], p0); p0 = fmaf(xa.w, w0[3], p0);
    p1 = fmaf(xb.x, w0[4], p1); p1 = fmaf(xb.y, w0[5], p1);
    p1 = fmaf(xb.z, w0[6], p1); p1 = fmaf(xb.w, w0[7], p1);
    p2 = fmaf(xc.x, w0[8], p2); p2 = fmaf(xc.y, w0[9], p2);
    p2 = fmaf(xc.z, w0[10], p2); p2 = fmaf(xc.w, w0[11], p2);
    float pre = hh_dot(h_lds, w, (p0 + p1) + p2);

    float a = ((g >> 6) == 2) ? tanh_(pre) : sig_(pre);
    gates[g] = a;
    if (g < CH) xs[nxt][g] = xreg;
    __syncthreads();
    if (g < CH) {
      int t2 = t + 2 * dt;
      t2 = (t2 < 0) ? 0 : ((t2 > T_LEN - 1) ? (T_LEN - 1) : t2);
      xreg = x[((size_t)b * CH + g) * T_LEN + t2];
    }
    if (g < HID) {
      float iv = gates[g], fv = gates[HID + g], gv = gates[2 * HID + g], ov = gates[3 * HID + g];
      c = fmaf(fv, c, iv * gv);
      float hv = ov * tanh_(c);
      h_lds[g] = hv;
      stv(&seq[((size_t)t * BATCH + b) * D2 + dir * HID + g], hv);
    }
    __syncthreads();
    t += dt;
  }
}

// ---------------------------------------------------------------------------
// Layers 1/2 input GEMM over a row range. WG = 128 thr, tile 64 rows x 256 cols.
// Per-thread 16x8 blocking; in[64][64] + w[256][32] XOR-swizzled in LDS (48KB).
// ---------------------------------------------------------------------------
template<typename ST>
__global__ __launch_bounds__(128) void k_gemm12(const ST* __restrict__ seq,
                                                const float* __restrict__ wih,
                                                const float* __restrict__ bih,
                                                const float* __restrict__ bhh,
                                                float* __restrict__ xw, int rowoff) {
  __shared__ float in_lds[64][64];
  __shared__ float w_lds[256][32];
  const int tid = threadIdx.x;
  const int cg = tid & 31;   // cols cg*8 .. cg*8+7
  const int rg = tid >> 5;   // rows rg*16 .. rg*16+15
  const size_t gr0 = (size_t)rowoff + (size_t)blockIdx.x * 64;  // global row base
  const size_t lr0 = (size_t)blockIdx.x * 64;                   // local (chunk) row base

  float acc[16][8];
#pragma unroll
  for (int rr = 0; rr < 16; ++rr)
#pragma unroll
    for (int j = 0; j < 8; ++j) acc[rr][j] = 0.f;

  for (int kh = 0; kh < 2; ++kh) {
    __syncthreads();
    // stage input cols [kh*64, kh*64+64) of 64 rows
    if constexpr (__is_same(ST, float)) {
      float4* dst = reinterpret_cast<float4*>(&in_lds[0][0]);
      for (int e = tid; e < 64 * 16; e += 128) {
        int row = e >> 4, cf4 = e & 15;
        dst[e] = *reinterpret_cast<const float4*>(&seq[(gr0 + row) * D2 + kh * 64 + cf4 * 4]);
      }
    } else {
      float* dstf = &in_lds[0][0];
      const __half2* src = reinterpret_cast<const __half2*>(seq);
      for (int e = tid; e < 64 * 32; e += 128) {
        int row = e >> 5, ch2 = e & 31;
        float2 f = __half22float2(src[(gr0 + row) * (D2 / 2) + kh * 32 + ch2]);
        dstf[row * 64 + ch2 * 2]     = f.x;
        dstf[row * 64 + ch2 * 2 + 1] = f.y;
      }
    }
    for (int kc2 = 0; kc2 < 2; ++kc2) {
      __syncthreads();
      int k0 = kh * 64 + kc2 * 32;
      for (int e4 = tid * 4; e4 < 256 * 32; e4 += 128 * 4) {
        int cc = e4 >> 5, kk = e4 & 31;
        float4 v = *reinterpret_cast<const float4*>(&wih[(size_t)cc * D2 + k0 + kk]);
        *reinterpret_cast<float4*>(&w_lds[cc][kk ^ (((cc >> 3) & 7) << 2)]) = v;
      }
      __syncthreads();
#pragma unroll
      for (int k4 = 0; k4 < 8; ++k4) {
        float4 wv[8];
#pragma unroll
        for (int j = 0; j < 8; ++j)
          wv[j] = *reinterpret_cast<const float4*>(&w_lds[cg * 8 + j][(k4 * 4) ^ ((cg & 7) << 2)]);
#pragma unroll
        for (int rr = 0; rr < 16; ++rr) {
          float4 iv = *reinterpret_cast<const float4*>(&in_lds[rg * 16 + rr][kc2 * 32 + k4 * 4]);
#pragma unroll
          for (int j = 0; j < 8; ++j) {
            acc[rr][j] = fmaf(iv.x, wv[j].x, acc[rr][j]);
            acc[rr][j] = fmaf(iv.y, wv[j].y, acc[rr][j]);
            acc[rr][j] = fmaf(iv.z, wv[j].z, acc[rr][j]);
            acc[rr][j] = fmaf(iv.w, wv[j].w, acc[rr][j]);
          }
        }
      }
    }
  }
  float bb[8];
#pragma unroll
  for (int j = 0; j < 8; ++j) bb[j] = bih[cg * 8 + j] + bhh[cg * 8 + j];
#pragma unroll
  for (int rr = 0; rr < 16; ++rr) {
    float* orow = xw + (lr0 + rg * 16 + rr) * G4 + cg * 8;
    float4 o0 = { acc[rr][0] + bb[0], acc[rr][1] + bb[1], acc[rr][2] + bb[2], acc[rr][3] + bb[3] };
    float4 o1 = { acc[rr][4] + bb[4], acc[rr][5] + bb[5], acc[rr][6] + bb[6], acc[rr][7] + bb[7] };
    *reinterpret_cast<float4*>(orow) = o0;
    *reinterpret_cast<float4*>(orow + 4) = o1;
  }
}

// ---------------------------------------------------------------------------
// Layers 1/2 recurrence over one time-chunk; h/c state carried in ws.
// WG per (dir,b): 128 WGs. xwF holds fwd chunk [tF0..], xwB bwd chunk.
// ---------------------------------------------------------------------------
template<typename ST>
__global__ __launch_bounds__(256) void k_recur12(const float* __restrict__ xwF,
                                                 const float* __restrict__ xwB,
                                                 const float* __restrict__ whh,
                                                 ST* __restrict__ seq,
                                                 float* __restrict__ hst, float* __restrict__ cst,
                                                 int initFlag, int tF0, int tB0, int TC) {
  int wg = blockIdx.x, dir = wg >> 6, b = wg & 63, g = threadIdx.x;
  const float* xw = dir ? xwB : xwF;
  const float* W = whh + (size_t)(dir * G4 + g) * HID;
  float w[HID];
#pragma unroll
  for (int k = 0; k < HID; ++k) w[k] = W[k];

  __shared__ __align__(16) float h_lds[HID];
  __shared__ float gates[G4];
  int sidx = (dir * BATCH + b) * HID + g;
  float c = 0.f;
  if (g < HID) {
    if (initFlag) { h_lds[g] = 0.f; }
    else          { h_lds[g] = hst[sidx]; c = cst[sidx]; }
  }
  __syncthreads();

  int t = dir ? tB0 : tF0;
  int dt = dir ? -1 : 1;
  int lt0 = dir ? (TC - 1) : 0;
  float xw_cur = xw[((size_t)lt0 * BATCH + b) * G4 + g];

  for (int it = 0; it < TC; ++it) {
    int ltn = dir ? (TC - 2 - it) : (it + 1);
    ltn = (ltn < 0) ? 0 : ((ltn > TC - 1) ? (TC - 1) : ltn);
    float xw_nxt = xw[((size_t)ltn * BATCH + b) * G4 + g];

    float pre = hh_dot(h_lds, w, xw_cur);
    float a = ((g >> 6) == 2) ? tanh_(pre) : sig_(pre);
    gates[g] = a;
    __syncthreads();
    if (g < HID) {
      float iv = gates[g], fv = gates[HID + g], gv = gates[2 * HID + g], ov = gates[3 * HID + g];
      c = fmaf(fv, c, iv * gv);
      float hv = ov * tanh_(c);
      h_lds[g] = hv;
      stv(&seq[((size_t)t * BATCH + b) * D2 + dir * HID + g], hv);
    }
    __syncthreads();
    xw_cur = xw_nxt;
    t += dt;
  }
  if (g < HID) { hst[sidx] = h_lds[g]; cst[sidx] = c; }
}

// ---------------------------------------------------------------------------
// Head MLP.
// ---------------------------------------------------------------------------
template<typename ST>
__global__ __launch_bounds__(128) void k_head(const ST* __restrict__ seq,
                                              const float* __restrict__ Wc1, const float* __restrict__ bc1,
                                              const float* __restrict__ Wc2, const float* __restrict__ bc2,
                                              const float* __restrict__ Wc3, const float* __restrict__ bc3,
                                              float* __restrict__ out) {
  int b = blockIdx.x;
  int tid = threadIdx.x;
  __shared__ float fin[D2], z1[D2], z2[HID];
  if (tid < HID) fin[tid] = ldv(&seq[((size_t)(T_LEN - 1) * BATCH + b) * D2 + tid]);
  else           fin[tid] = ldv(&seq[(size_t)b * D2 + tid]);
  __syncthreads();
  float s = bc1[tid];
  for (int k = 0; k < D2; ++k) s = fmaf(fin[k], Wc1[(size_t)tid * D2 + k], s);
  z1[tid] = fmaxf(s, 0.f);
  __syncthreads();
  if (tid < HID) {
    float s2 = bc2[tid];
    for (int k = 0; k < D2; ++k) s2 = fmaf(z1[k], Wc2[(size_t)tid * D2 + k], s2);
    z2[tid] = fmaxf(s2, 0.f);
  }
  __syncthreads();
  if (tid < 20) {
    float s3 = bc3[tid];
    for (int k = 0; k < HID; ++k) s3 = fmaf(z2[k], Wc3[(size_t)tid * HID + k], s3);
    out[b * 20 + tid] = s3;
  }
}

// ---------------------------------------------------------------------------
template<typename ST>
static void run_all(const float* x, const float* Wp, const float* bp,
                    const float* w_ih0, const float* w_hh0, const float* b_ih0, const float* b_hh0,
                    const float* w_ih12, const float* w_hh12, const float* b_ih12, const float* b_hh12,
                    const float* Wc1, const float* bc1, const float* Wc2, const float* bc2,
                    const float* Wc3, const float* bc3,
                    float* out, char* ws, int TC, hipStream_t stream) {
  ST* seqA = (ST*)ws;
  ST* seqB = seqA + (size_t)NROW * D2;
  uintptr_t up = ((uintptr_t)(seqB + (size_t)NROW * D2) + 255) & ~(uintptr_t)255;
  float* xwF = (float*)up;
  float* xwB = xwF + (size_t)TC * BATCH * G4;
  float* hst = xwB + (size_t)TC * BATCH * G4;
  float* cst = hst + 2 * BATCH * HID;
  float* w0p = cst + 2 * BATCH * HID;
  float* b0p = w0p + 2 * G4 * CH;

  hipLaunchKernelGGL(k_prep0, dim3(2), dim3(256), 0, stream, Wp, bp, w_ih0, b_ih0, b_hh0, w0p, b0p);
  hipLaunchKernelGGL(k_recur0<ST>, dim3(128), dim3(256), 0, stream, x, w0p, b0p, w_hh0, seqA);

  int NC = T_LEN / TC;
  for (int l = 0; l < 2; ++l) {
    const float* wih0d = w_ih12 + (size_t)(l * 2) * G4 * D2;
    const float* wih1d = wih0d + (size_t)G4 * D2;
    const float* whh_l = w_hh12 + (size_t)(l * 2) * G4 * HID;
    const float* bi0 = b_ih12 + (size_t)(l * 2) * G4;
    const float* bh0 = b_hh12 + (size_t)(l * 2) * G4;
    ST* sin  = (l == 0) ? seqA : seqB;
    ST* sout = (l == 0) ? seqB : seqA;
    for (int c = 0; c < NC; ++c) {
      int cb = NC - 1 - c;
      hipLaunchKernelGGL(k_gemm12<ST>, dim3(TC), dim3(128), 0, stream,
                         sin, wih0d, bi0, bh0, xwF, c * TC * BATCH);
      hipLaunchKernelGGL(k_gemm12<ST>, dim3(TC), dim3(128), 0, stream,
                         sin, wih1d, bi0 + G4, bh0 + G4, xwB, cb * TC * BATCH);
      hipLaunchKernelGGL(k_recur12<ST>, dim3(128), dim3(256), 0, stream,
                         xwF, xwB, whh_l, sout, hst, cst, (c == 0) ? 1 : 0,
                         c * TC, cb * TC + TC - 1, TC);
    }
  }
  hipLaunchKernelGGL(k_head<ST>, dim3(BATCH), dim3(128), 0, stream,
                     seqA, Wc1, bc1, Wc2, bc2, Wc3, bc3, out);
}

extern "C" void kernel_launch(void* const* d_in, const int* in_sizes, int n_in,
                              void* d_out, int out_size, void* d_ws, size_t ws_size,
                              hipStream_t stream) {
  const float* x      = (const float*)d_in[0];
  const float* Wp     = (const float*)d_in[1];
  const float* bp     = (const float*)d_in[2];
  const float* w_ih0  = (const float*)d_in[3];
  const float* w_hh0  = (const float*)d_in[4];
  const float* b_ih0  = (const float*)d_in[5];
  const float* b_hh0  = (const float*)d_in[6];
  const float* w_ih12 = (const float*)d_in[7];
  const float* w_hh12 = (const float*)d_in[8];
  const float* b_ih12 = (const float*)d_in[9];
  const float* b_hh12 = (const float*)d_in[10];
  const float* Wc1    = (const float*)d_in[11];
  const float* bc1    = (const float*)d_in[12];
  const float* Wc2    = (const float*)d_in[13];
  const float* bc2    = (const float*)d_in[14];
  const float* Wc3    = (const float*)d_in[15];
  const float* bc3    = (const float*)d_in[16];
  float* out = (float*)d_out;
  char* ws = (char*)d_ws;

  auto need = [](bool half, int TC) -> size_t {
    size_t seqb  = (size_t)NROW * D2 * (half ? 2 : 4) * 2;   // two seq buffers
    size_t chunk = (size_t)2 * TC * BATCH * G4 * 4;          // xwF + xwB
    size_t small = (size_t)(2 * 2 * BATCH * HID + 2 * G4 * CH + 2 * G4) * 4;
    return seqb + chunk + small + 1024;
  };

  struct Opt { bool h; int tc; };
  const Opt opts[] = { {false,625},{false,500},{false,250},{false,125},{false,100},
                       {true,625},{true,500},{true,250},{true,125},{true,100},{true,50},{true,25} };
  bool useHalf = true; int TC = 25;
  for (const Opt& o : opts) {
    if (need(o.h, o.tc) <= ws_size) { useHalf = o.h; TC = o.tc; break; }
  }

  if (!useHalf)
    run_all<float>(x, Wp, bp, w_ih0, w_hh0, b_ih0, b_hh0, w_ih12, w_hh12, b_ih12, b_hh12,
                   Wc1, bc1, Wc2, bc2, Wc3, bc3, out, ws, TC, stream);
  else
    run_all<__half>(x, Wp, bp, w_ih0, w_hh0, b_ih0, b_hh0, w_ih12, w_hh12, b_ih12, b_hh12,
                    Wc1, bc1, Wc2, bc2, Wc3, bc3, out, ws, TC, stream);
}